// Round 1
// baseline (646.906 us; speedup 1.0000x reference)
//
#include <hip/hip_runtime.h>
#include <hip/hip_bf16.h>

// ---------------------------------------------------------------------------
// GAT 2-layer forward on MI355X.
// Layer1: GATConv(256 -> 128, heads=2, concat) + bias + ReLU
// Layer2: GATConv(256 -> 128, heads=1, mean over 1 head = identity) + bias
// Softmax over incoming-edge neighborhoods (incl. self loops).
// Implementation: fp32 tiled GEMM (no fp32 MFMA on CDNA4), CSR build via
// counting sort each call, pull-based aggregation with end-normalization
// (softmax shift-invariance lets us skip segment_max; sum-at-end lets us
// skip the separate denom pass).
// ---------------------------------------------------------------------------

#define GEMM_BM 64
#define GEMM_BN 64
#define GEMM_BK 32
#define GEMM_PAD 4

__global__ __launch_bounds__(256) void gemm_nt_kernel(
    const float* __restrict__ A,   // [M,K] row-major
    const float* __restrict__ B,   // [N,K] row-major (i.e. C = A @ B^T)
    float* __restrict__ C,         // [M,N]
    int M, int N, int K)
{
    __shared__ float As[GEMM_BK][GEMM_BM + GEMM_PAD];
    __shared__ float Bs[GEMM_BK][GEMM_BN + GEMM_PAD];

    const int u  = threadIdx.x;
    const int m0 = blockIdx.x * GEMM_BM;
    const int n0 = blockIdx.y * GEMM_BN;
    const int tx = u & 15;        // 0..15 -> n
    const int ty = u >> 4;        // 0..15 -> m

    float acc[4][4] = {};

    for (int k0 = 0; k0 < K; k0 += GEMM_BK) {
        // cooperative load: 64x32 tile each of A and B, float4 per thread x2
#pragma unroll
        for (int r = 0; r < 2; ++r) {
            const int f   = u + r * 256;      // 0..511
            const int row = f >> 3;           // 0..63
            const int kc4 = (f & 7) << 2;     // 0,4,...,28
            float4 va = make_float4(0.f, 0.f, 0.f, 0.f);
            const int gm = m0 + row;
            if (gm < M)
                va = *reinterpret_cast<const float4*>(A + (long)gm * K + k0 + kc4);
            As[kc4 + 0][row] = va.x;
            As[kc4 + 1][row] = va.y;
            As[kc4 + 2][row] = va.z;
            As[kc4 + 3][row] = va.w;
            const int gn = n0 + row;          // grid.y covers exactly N/64
            float4 vb = *reinterpret_cast<const float4*>(B + (long)gn * K + k0 + kc4);
            Bs[kc4 + 0][row] = vb.x;
            Bs[kc4 + 1][row] = vb.y;
            Bs[kc4 + 2][row] = vb.z;
            Bs[kc4 + 3][row] = vb.w;
        }
        __syncthreads();

#pragma unroll
        for (int k = 0; k < GEMM_BK; ++k) {
            const float4 a4 = *reinterpret_cast<const float4*>(&As[k][ty << 2]);
            const float4 b4 = *reinterpret_cast<const float4*>(&Bs[k][tx << 2]);
            const float av[4] = {a4.x, a4.y, a4.z, a4.w};
            const float bv[4] = {b4.x, b4.y, b4.z, b4.w};
#pragma unroll
            for (int i = 0; i < 4; ++i)
#pragma unroll
                for (int j = 0; j < 4; ++j)
                    acc[i][j] += av[i] * bv[j];
        }
        __syncthreads();
    }

#pragma unroll
    for (int i = 0; i < 4; ++i) {
        const int gm = m0 + (ty << 2) + i;
        if (gm < M) {
            float4 v = make_float4(acc[i][0], acc[i][1], acc[i][2], acc[i][3]);
            *reinterpret_cast<float4*>(C + (long)gm * N + n0 + (tx << 2)) = v;
        }
    }
}

// --- CSR build --------------------------------------------------------------

__global__ void count_kernel(const int* __restrict__ dst, int* __restrict__ deg, int E)
{
    const int e = blockIdx.x * blockDim.x + threadIdx.x;
    if (e < E) atomicAdd(&deg[dst[e]], 1);
}

__global__ __launch_bounds__(1024) void scan_kernel(
    const int* __restrict__ deg, int* __restrict__ off, int* __restrict__ cursor, int n)
{
    __shared__ int sdata[1024];
    const int t = threadIdx.x;
    const int chunk = (n + 1023) >> 10;
    const int s = t * chunk;
    const int e = min(s + chunk, n);
    int sum = 0;
    for (int i = s; i < e; ++i) sum += deg[i] + 1;   // +1: self loop
    sdata[t] = sum;
    __syncthreads();
    for (int o = 1; o < 1024; o <<= 1) {
        int v = 0;
        if (t >= o) v = sdata[t - o];
        __syncthreads();
        sdata[t] += v;
        __syncthreads();
    }
    int run = (t == 0) ? 0 : sdata[t - 1];
    for (int i = s; i < e; ++i) {
        off[i] = run;
        cursor[i] = run;
        run += deg[i] + 1;
    }
    if (t == 1023) off[n] = sdata[1023];
}

__global__ void scatter_kernel(const int* __restrict__ src, const int* __restrict__ dst,
                               int* __restrict__ cursor, int* __restrict__ csr_src,
                               int E, int N)
{
    const int e = blockIdx.x * blockDim.x + threadIdx.x;
    if (e < E) {
        const int d = dst[e];
        const int p = atomicAdd(&cursor[d], 1);
        csr_src[p] = src[e];
    } else if (e < E + N) {
        const int nn = e - E;
        const int p = atomicAdd(&cursor[nn], 1);
        csr_src[p] = nn;
    }
}

// --- attention logits: a[n,h] = sum_c h[n,h,c] * att[h,c]  (C = 128) -------

template <int H>
__global__ __launch_bounds__(256) void att_kernel(
    const float* __restrict__ h,      // [N, H*128]
    const float* __restrict__ att_s,  // [H*128]
    const float* __restrict__ att_d,  // [H*128]
    float* __restrict__ a_s,          // [N*H]
    float* __restrict__ a_d,          // [N*H]
    int N)
{
    const int g = (blockIdx.x * 256 + threadIdx.x) >> 6;  // wave id = n*H + hh
    const int l = threadIdx.x & 63;
    if (g >= N * H) return;
    const int n  = g / H;
    const int hh = g % H;
    const float* row = h + (long)n * (H * 128) + hh * 128;
    const float* asv = att_s + hh * 128;
    const float* adv = att_d + hh * 128;
    const float v0 = row[l], v1 = row[l + 64];
    float ss = v0 * asv[l] + v1 * asv[l + 64];
    float dd = v0 * adv[l] + v1 * adv[l + 64];
#pragma unroll
    for (int o = 32; o > 0; o >>= 1) {
        ss += __shfl_xor(ss, o, 64);
        dd += __shfl_xor(dd, o, 64);
    }
    if (l == 0) { a_s[g] = ss; a_d[g] = dd; }
}

// --- pull-based aggregation -------------------------------------------------
// out[d, h*C+c] = (sum_e w_eh * h[s_e, h*C+c]) / (sum_e w_eh)  [+bias][relu]
// w_eh = exp(leaky_relu(a_s[s,h] + a_d[d,h]))  -- softmax shift-invariant.

#define AGG_TILE 64

template <int H, int C, bool RELU>
__global__ __launch_bounds__(H * C) void aggregate_kernel(
    const int* __restrict__ csr_off,
    const int* __restrict__ csr_src,
    const float* __restrict__ h,     // [N, H*C]
    const float* __restrict__ a_s,   // [N, H]
    const float* __restrict__ a_d,   // [N, H]
    const float* __restrict__ bias,  // [H*C]
    float* __restrict__ out)         // [N, H*C]
{
    const int d  = blockIdx.x;
    const int t  = threadIdx.x;
    const int hh = t / C;

    __shared__ int   s_src[AGG_TILE];
    __shared__ float s_w[AGG_TILE][H];

    const int beg = csr_off[d];
    const int end = csr_off[d + 1];

    float acc = 0.f, wsum = 0.f;

    for (int base = beg; base < end; base += AGG_TILE) {
        const int len = min(AGG_TILE, end - base);
        if (t < len) {
            const int s = csr_src[base + t];
            s_src[t] = s;
#pragma unroll
            for (int h2 = 0; h2 < H; ++h2) {
                float logit = a_s[s * H + h2] + a_d[d * H + h2];
                logit = logit > 0.f ? logit : 0.2f * logit;
                s_w[t][h2] = __expf(logit);
            }
        }
        __syncthreads();
        for (int j = 0; j < len; ++j) {
            const float w = s_w[j][hh];
            const int   s = s_src[j];
            acc  += w * h[(long)s * (H * C) + t];
            wsum += w;
        }
        __syncthreads();
    }

    float r = acc / wsum + bias[t];
    if (RELU) r = r > 0.f ? r : 0.f;
    out[(long)d * (H * C) + t] = r;
}

// ---------------------------------------------------------------------------

extern "C" void kernel_launch(void* const* d_in, const int* in_sizes, int n_in,
                              void* d_out, int out_size, void* d_ws, size_t ws_size,
                              hipStream_t stream)
{
    const float* x    = (const float*)d_in[0];
    const int*   eidx = (const int*)d_in[1];
    const float* W1   = (const float*)d_in[2];
    const float* as1  = (const float*)d_in[3];
    const float* ad1  = (const float*)d_in[4];
    const float* b1   = (const float*)d_in[5];
    const float* W2   = (const float*)d_in[6];
    const float* as2  = (const float*)d_in[7];
    const float* ad2  = (const float*)d_in[8];
    const float* b2   = (const float*)d_in[9];
    float* out = (float*)d_out;

    const int IN_FEATS = 256;
    const int N = in_sizes[0] / IN_FEATS;    // 50000
    const int E = in_sizes[1] / 2;           // 800000

    const int* esrc = eidx;
    const int* edst = eidx + E;

    // workspace carve-up (256B aligned)
    size_t off = 0;
    auto alloc = [&](size_t bytes) -> void* {
        void* p = (char*)d_ws + off;
        off += (bytes + 255) & ~(size_t)255;
        return p;
    };
    float* h1      = (float*)alloc((size_t)N * 256 * 4);
    float* out1    = (float*)alloc((size_t)N * 256 * 4);
    float* h2      = (float*)alloc((size_t)N * 128 * 4);
    float* a1s     = (float*)alloc((size_t)N * 2 * 4);
    float* a1d     = (float*)alloc((size_t)N * 2 * 4);
    float* a2s     = (float*)alloc((size_t)N * 4);
    float* a2d     = (float*)alloc((size_t)N * 4);
    int*   deg     = (int*)alloc((size_t)N * 4);
    int*   cursor  = (int*)alloc((size_t)N * 4);
    int*   csr_off = (int*)alloc((size_t)(N + 1) * 4);
    int*   csr_src = (int*)alloc((size_t)(E + N) * 4);

    // --- CSR build (graph is identical both layers; build once) ---
    hipMemsetAsync(deg, 0, (size_t)N * 4, stream);
    count_kernel<<<(E + 255) / 256, 256, 0, stream>>>(edst, deg, E);
    scan_kernel<<<1, 1024, 0, stream>>>(deg, csr_off, cursor, N);
    scatter_kernel<<<(E + N + 255) / 256, 256, 0, stream>>>(esrc, edst, cursor, csr_src, E, N);

    // --- layer 1 ---
    {
        dim3 grid((N + GEMM_BM - 1) / GEMM_BM, 256 / GEMM_BN);
        gemm_nt_kernel<<<grid, 256, 0, stream>>>(x, W1, h1, N, 256, 256);
    }
    {
        const int waves = N * 2;
        att_kernel<2><<<(waves + 3) / 4, 256, 0, stream>>>(h1, as1, ad1, a1s, a1d, N);
    }
    aggregate_kernel<2, 128, true><<<N, 256, 0, stream>>>(csr_off, csr_src, h1, a1s, a1d, b1, out1);

    // --- layer 2 ---
    {
        dim3 grid((N + GEMM_BM - 1) / GEMM_BM, 128 / GEMM_BN);
        gemm_nt_kernel<<<grid, 256, 0, stream>>>(out1, W2, h2, N, 128, 256);
    }
    {
        const int waves = N;
        att_kernel<1><<<(waves + 3) / 4, 256, 0, stream>>>(h2, as2, ad2, a2s, a2d, N);
    }
    aggregate_kernel<1, 128, false><<<N, 128, 0, stream>>>(csr_off, csr_src, h2, a2s, a2d, b2, out);
}

// Round 2
// 447.369 us; speedup vs baseline: 1.4460x; 1.4460x over previous
//
#include <hip/hip_runtime.h>
#include <hip/hip_bf16.h>

// ---------------------------------------------------------------------------
// GAT 2-layer forward on MI355X (gfx950).
// R1: (a) all intermediate features stored fp16 -> aggregate traffic halved;
//     (b) GEMMs use mfma_f32_16x16x32_f16 (fp32 accumulate), converting
//         fp32 inputs to fp16 during LDS staging.
// Softmax shift-invariance -> no segment_max; normalize once at the end.
// ---------------------------------------------------------------------------

typedef _Float16 half8v __attribute__((ext_vector_type(8)));
typedef _Float16 half4v __attribute__((ext_vector_type(4)));
typedef _Float16 half2v __attribute__((ext_vector_type(2)));
typedef float f32x4 __attribute__((ext_vector_type(4)));

// --- MFMA GEMM: C[M,N](f16) = A[M,K] @ B[N,K]^T, B fp32 weights ------------
// 128x128 tile, BK=32, 256 threads = 4 waves (2x2), each wave 64x64.

template <typename TA>
__global__ __launch_bounds__(256) void gemm_mfma_kernel(
    const TA* __restrict__ A,      // [M,K] row-major (float or _Float16)
    const float* __restrict__ B,   // [N,K] row-major fp32 weights
    _Float16* __restrict__ C,      // [M,N] fp16 out
    int M, int N, int K)
{
    constexpr int BM = 128, BK = 32, LDA = 40;   // 40 f16 = 80 B = 5*16 B
    __shared__ _Float16 Ah[BM * LDA];
    __shared__ _Float16 Bh[BM * LDA];

    const int tid = threadIdx.x;
    const int m0 = blockIdx.x * BM;
    const int n0 = blockIdx.y * BM;
    const int w  = tid >> 6;
    const int l  = tid & 63;
    const int wm = (w >> 1) * 64;
    const int wn = (w & 1) * 64;
    const int lr = l & 15;        // fragment row-within-16
    const int lq = l >> 4;        // quad -> k-offset *8

    f32x4 acc[4][4] = {};

    for (int k0 = 0; k0 < K; k0 += BK) {
        // ---- stage A tile (128 x 32) ----
        if constexpr (__is_same(TA, float)) {
#pragma unroll
            for (int it = 0; it < 4; ++it) {
                const int row = (tid >> 3) + it * 32;
                const int gm  = min(m0 + row, M - 1);
                const int c4  = (tid & 7) * 4;
                float4 v = *reinterpret_cast<const float4*>(A + (long)gm * K + k0 + c4);
                half4v o = { (_Float16)v.x, (_Float16)v.y, (_Float16)v.z, (_Float16)v.w };
                *reinterpret_cast<half4v*>(&Ah[row * LDA + c4]) = o;
            }
        } else {
#pragma unroll
            for (int it = 0; it < 2; ++it) {
                const int row = (tid >> 2) + it * 64;
                const int gm  = min(m0 + row, M - 1);
                const int c8  = (tid & 3) * 8;
                float4 v = *reinterpret_cast<const float4*>((const char*)A + ((long)gm * K + k0 + c8) * 2);
                *reinterpret_cast<float4*>(&Ah[row * LDA + c8]) = v;
            }
        }
        // ---- stage B tile (128 x 32, always fp32 in) ----
#pragma unroll
        for (int it = 0; it < 4; ++it) {
            const int row = (tid >> 3) + it * 32;
            const int c4  = (tid & 7) * 4;
            float4 v = *reinterpret_cast<const float4*>(B + (long)(n0 + row) * K + k0 + c4);
            half4v o = { (_Float16)v.x, (_Float16)v.y, (_Float16)v.z, (_Float16)v.w };
            *reinterpret_cast<half4v*>(&Bh[row * LDA + c4]) = o;
        }
        __syncthreads();

        half8v af[4], bf[4];
#pragma unroll
        for (int i = 0; i < 4; ++i)
            af[i] = *reinterpret_cast<const half8v*>(&Ah[(wm + i * 16 + lr) * LDA + lq * 8]);
#pragma unroll
        for (int j = 0; j < 4; ++j)
            bf[j] = *reinterpret_cast<const half8v*>(&Bh[(wn + j * 16 + lr) * LDA + lq * 8]);
#pragma unroll
        for (int i = 0; i < 4; ++i)
#pragma unroll
            for (int j = 0; j < 4; ++j)
                acc[i][j] = __builtin_amdgcn_mfma_f32_16x16x32_f16(af[i], bf[j], acc[i][j], 0, 0, 0);
        __syncthreads();
    }

    // epilogue: D[m = wm+i*16+lq*4+r][n = wn+j*16+lr]
#pragma unroll
    for (int i = 0; i < 4; ++i) {
        const int gm_base = m0 + wm + i * 16 + lq * 4;
#pragma unroll
        for (int r = 0; r < 4; ++r) {
            const int gm = gm_base + r;
            if (gm < M) {
#pragma unroll
                for (int j = 0; j < 4; ++j) {
                    const int gn = n0 + wn + j * 16 + lr;
                    C[(long)gm * N + gn] = (_Float16)acc[i][j][r];
                }
            }
        }
    }
}

// --- CSR build --------------------------------------------------------------

__global__ void count_kernel(const int* __restrict__ dst, int* __restrict__ deg, int E)
{
    const int e = blockIdx.x * blockDim.x + threadIdx.x;
    if (e < E) atomicAdd(&deg[dst[e]], 1);
}

__global__ __launch_bounds__(1024) void scan_kernel(
    const int* __restrict__ deg, int* __restrict__ off, int* __restrict__ cursor, int n)
{
    __shared__ int sdata[1024];
    const int t = threadIdx.x;
    const int chunk = (n + 1023) >> 10;
    const int s = t * chunk;
    const int e = min(s + chunk, n);
    int sum = 0;
    for (int i = s; i < e; ++i) sum += deg[i] + 1;   // +1: self loop
    sdata[t] = sum;
    __syncthreads();
    for (int o = 1; o < 1024; o <<= 1) {
        int v = 0;
        if (t >= o) v = sdata[t - o];
        __syncthreads();
        sdata[t] += v;
        __syncthreads();
    }
    int run = (t == 0) ? 0 : sdata[t - 1];
    for (int i = s; i < e; ++i) {
        off[i] = run;
        cursor[i] = run;
        run += deg[i] + 1;
    }
    if (t == 1023) off[n] = sdata[1023];
}

__global__ void scatter_kernel(const int* __restrict__ src, const int* __restrict__ dst,
                               int* __restrict__ cursor, int* __restrict__ csr_src,
                               int E, int N)
{
    const int e = blockIdx.x * blockDim.x + threadIdx.x;
    if (e < E) {
        const int d = dst[e];
        const int p = atomicAdd(&cursor[d], 1);
        csr_src[p] = src[e];
    } else if (e < E + N) {
        const int nn = e - E;
        const int p = atomicAdd(&cursor[nn], 1);
        csr_src[p] = nn;
    }
}

// --- attention logits: a[n,h] = sum_c h[n,h,c]*att[h,c], C=128, fp16 h ------

template <int H>
__global__ __launch_bounds__(256) void att_kernel(
    const _Float16* __restrict__ h,   // [N, H*128]
    const float* __restrict__ att_s,  // [H*128]
    const float* __restrict__ att_d,  // [H*128]
    float* __restrict__ a_s,          // [N*H]
    float* __restrict__ a_d,          // [N*H]
    int N)
{
    const int g = (blockIdx.x * 256 + threadIdx.x) >> 6;  // wave id = n*H + hh
    const int l = threadIdx.x & 63;
    if (g >= N * H) return;
    const int n  = g / H;
    const int hh = g % H;
    const _Float16* row = h + (long)n * (H * 128) + hh * 128;
    const float* asv = att_s + hh * 128;
    const float* adv = att_d + hh * 128;
    const float v0 = (float)row[l], v1 = (float)row[l + 64];
    float ss = v0 * asv[l] + v1 * asv[l + 64];
    float dd = v0 * adv[l] + v1 * adv[l + 64];
#pragma unroll
    for (int o = 32; o > 0; o >>= 1) {
        ss += __shfl_xor(ss, o, 64);
        dd += __shfl_xor(dd, o, 64);
    }
    if (l == 0) { a_s[g] = ss; a_d[g] = dd; }
}

// --- pull-based aggregation (fp16 messages, fp32 accumulate) ---------------
// out[d, c] = (sum_e w_eh * h[s_e, c]) / (sum_e w_eh) [+bias][relu]
// w_eh = exp(leaky_relu(a_s[s,h] + a_d[d,h])); thread t handles cols 2t,2t+1.

#define AGG_TILE 64

template <int H, int C, bool RELU, typename TOUT>
__global__ __launch_bounds__(H * C / 2) void aggregate_kernel(
    const int* __restrict__ csr_off,
    const int* __restrict__ csr_src,
    const _Float16* __restrict__ h,  // [N, H*C] fp16
    const float* __restrict__ a_s,   // [N, H]
    const float* __restrict__ a_d,   // [N, H]
    const float* __restrict__ bias,  // [H*C]
    TOUT* __restrict__ out)          // [N, H*C]
{
    const int d  = blockIdx.x;
    const int t  = threadIdx.x;
    const int hh = (2 * t) / C;

    __shared__ int   s_src[AGG_TILE];
    __shared__ float s_w[AGG_TILE][H];

    const int beg = csr_off[d];
    const int end = csr_off[d + 1];

    float accx = 0.f, accy = 0.f, wsum = 0.f;

    for (int base = beg; base < end; base += AGG_TILE) {
        const int len = min(AGG_TILE, end - base);
        if (t < len) {
            const int s = csr_src[base + t];
            s_src[t] = s;
#pragma unroll
            for (int h2 = 0; h2 < H; ++h2) {
                float logit = a_s[s * H + h2] + a_d[d * H + h2];
                logit = logit > 0.f ? logit : 0.2f * logit;
                s_w[t][h2] = __expf(logit);
            }
        }
        __syncthreads();
        for (int j = 0; j < len; ++j) {
            const float w = s_w[j][hh];
            const int   s = s_src[j];
            half2v hv = *reinterpret_cast<const half2v*>(h + (long)s * (H * C) + 2 * t);
            accx += w * (float)hv.x;
            accy += w * (float)hv.y;
            wsum += w;
        }
        __syncthreads();
    }

    const float2 b = *reinterpret_cast<const float2*>(bias + 2 * t);
    float rx = accx / wsum + b.x;
    float ry = accy / wsum + b.y;
    if (RELU) { rx = rx > 0.f ? rx : 0.f; ry = ry > 0.f ? ry : 0.f; }
    if constexpr (__is_same(TOUT, _Float16)) {
        half2v o = { (_Float16)rx, (_Float16)ry };
        *reinterpret_cast<half2v*>(out + (long)d * (H * C) + 2 * t) = o;
    } else {
        float2 o = make_float2(rx, ry);
        *reinterpret_cast<float2*>(out + (long)d * (H * C) + 2 * t) = o;
    }
}

// ---------------------------------------------------------------------------

extern "C" void kernel_launch(void* const* d_in, const int* in_sizes, int n_in,
                              void* d_out, int out_size, void* d_ws, size_t ws_size,
                              hipStream_t stream)
{
    const float* x    = (const float*)d_in[0];
    const int*   eidx = (const int*)d_in[1];
    const float* W1   = (const float*)d_in[2];
    const float* as1  = (const float*)d_in[3];
    const float* ad1  = (const float*)d_in[4];
    const float* b1   = (const float*)d_in[5];
    const float* W2   = (const float*)d_in[6];
    const float* as2  = (const float*)d_in[7];
    const float* ad2  = (const float*)d_in[8];
    const float* b2   = (const float*)d_in[9];
    float* out = (float*)d_out;

    const int IN_FEATS = 256;
    const int N = in_sizes[0] / IN_FEATS;    // 50000
    const int E = in_sizes[1] / 2;           // 800000

    const int* esrc = eidx;
    const int* edst = eidx + E;

    size_t off = 0;
    auto alloc = [&](size_t bytes) -> void* {
        void* p = (char*)d_ws + off;
        off += (bytes + 255) & ~(size_t)255;
        return p;
    };
    _Float16* h1h   = (_Float16*)alloc((size_t)N * 256 * 2);
    _Float16* o1h   = (_Float16*)alloc((size_t)N * 256 * 2);
    _Float16* h2h   = (_Float16*)alloc((size_t)N * 128 * 2);
    float* a1s      = (float*)alloc((size_t)N * 2 * 4);
    float* a1d      = (float*)alloc((size_t)N * 2 * 4);
    float* a2s      = (float*)alloc((size_t)N * 4);
    float* a2d      = (float*)alloc((size_t)N * 4);
    int*   deg      = (int*)alloc((size_t)N * 4);
    int*   cursor   = (int*)alloc((size_t)N * 4);
    int*   csr_off  = (int*)alloc((size_t)(N + 1) * 4);
    int*   csr_src  = (int*)alloc((size_t)(E + N) * 4);

    // --- CSR build (same graph both layers) ---
    hipMemsetAsync(deg, 0, (size_t)N * 4, stream);
    count_kernel<<<(E + 255) / 256, 256, 0, stream>>>(edst, deg, E);
    scan_kernel<<<1, 1024, 0, stream>>>(deg, csr_off, cursor, N);
    scatter_kernel<<<(E + N + 255) / 256, 256, 0, stream>>>(esrc, edst, cursor, csr_src, E, N);

    // --- layer 1 ---
    {
        dim3 grid((N + 127) / 128, 256 / 128);
        gemm_mfma_kernel<float><<<grid, 256, 0, stream>>>(x, W1, h1h, N, 256, 256);
    }
    att_kernel<2><<<(N * 2 + 3) / 4, 256, 0, stream>>>(h1h, as1, ad1, a1s, a1d, N);
    aggregate_kernel<2, 128, true, _Float16><<<N, 128, 0, stream>>>(
        csr_off, csr_src, h1h, a1s, a1d, b1, o1h);

    // --- layer 2 ---
    {
        dim3 grid((N + 127) / 128, 128 / 128);
        gemm_mfma_kernel<_Float16><<<grid, 256, 0, stream>>>(o1h, W2, h2h, N, 128, 256);
    }
    att_kernel<1><<<(N + 3) / 4, 256, 0, stream>>>(h2h, as2, ad2, a2s, a2d, N);
    aggregate_kernel<1, 128, false, float><<<N, 64, 0, stream>>>(
        csr_off, csr_src, h2h, a2s, a2d, b2, out);
}

// Round 3
// 359.164 us; speedup vs baseline: 1.8011x; 1.2456x over previous
//
#include <hip/hip_runtime.h>
#include <hip/hip_bf16.h>

// ---------------------------------------------------------------------------
// GAT 2-layer forward on MI355X (gfx950).
// R2: (a) 3-phase device-wide scan replaces the 110us single-block scan;
//     (b) aggregate uses half4 loads (64-thread blocks).
// fp16 intermediates, MFMA f16 GEMMs, softmax shift-invariance (no max pass),
// end-normalization (no separate denom pass).
// ---------------------------------------------------------------------------

typedef _Float16 half8v __attribute__((ext_vector_type(8)));
typedef _Float16 half4v __attribute__((ext_vector_type(4)));
typedef _Float16 half2v __attribute__((ext_vector_type(2)));
typedef float f32x4 __attribute__((ext_vector_type(4)));

// --- MFMA GEMM: C[M,N](f16) = A[M,K] @ B[N,K]^T, B fp32 weights ------------
// 128x128 tile, BK=32, 256 threads = 4 waves (2x2), each wave 64x64.

template <typename TA>
__global__ __launch_bounds__(256) void gemm_mfma_kernel(
    const TA* __restrict__ A,      // [M,K] row-major (float or _Float16)
    const float* __restrict__ B,   // [N,K] row-major fp32 weights
    _Float16* __restrict__ C,      // [M,N] fp16 out
    int M, int N, int K)
{
    constexpr int BM = 128, BK = 32, LDA = 40;   // 40 f16 = 80 B = 5*16 B
    __shared__ _Float16 Ah[BM * LDA];
    __shared__ _Float16 Bh[BM * LDA];

    const int tid = threadIdx.x;
    const int m0 = blockIdx.x * BM;
    const int n0 = blockIdx.y * BM;
    const int w  = tid >> 6;
    const int l  = tid & 63;
    const int wm = (w >> 1) * 64;
    const int wn = (w & 1) * 64;
    const int lr = l & 15;        // fragment row-within-16
    const int lq = l >> 4;        // quad -> k-offset *8

    f32x4 acc[4][4] = {};

    for (int k0 = 0; k0 < K; k0 += BK) {
        if constexpr (__is_same(TA, float)) {
#pragma unroll
            for (int it = 0; it < 4; ++it) {
                const int row = (tid >> 3) + it * 32;
                const int gm  = min(m0 + row, M - 1);
                const int c4  = (tid & 7) * 4;
                float4 v = *reinterpret_cast<const float4*>(A + (long)gm * K + k0 + c4);
                half4v o = { (_Float16)v.x, (_Float16)v.y, (_Float16)v.z, (_Float16)v.w };
                *reinterpret_cast<half4v*>(&Ah[row * LDA + c4]) = o;
            }
        } else {
#pragma unroll
            for (int it = 0; it < 2; ++it) {
                const int row = (tid >> 2) + it * 64;
                const int gm  = min(m0 + row, M - 1);
                const int c8  = (tid & 3) * 8;
                float4 v = *reinterpret_cast<const float4*>((const char*)A + ((long)gm * K + k0 + c8) * 2);
                *reinterpret_cast<float4*>(&Ah[row * LDA + c8]) = v;
            }
        }
#pragma unroll
        for (int it = 0; it < 4; ++it) {
            const int row = (tid >> 3) + it * 32;
            const int c4  = (tid & 7) * 4;
            float4 v = *reinterpret_cast<const float4*>(B + (long)(n0 + row) * K + k0 + c4);
            half4v o = { (_Float16)v.x, (_Float16)v.y, (_Float16)v.z, (_Float16)v.w };
            *reinterpret_cast<half4v*>(&Bh[row * LDA + c4]) = o;
        }
        __syncthreads();

        half8v af[4], bf[4];
#pragma unroll
        for (int i = 0; i < 4; ++i)
            af[i] = *reinterpret_cast<const half8v*>(&Ah[(wm + i * 16 + lr) * LDA + lq * 8]);
#pragma unroll
        for (int j = 0; j < 4; ++j)
            bf[j] = *reinterpret_cast<const half8v*>(&Bh[(wn + j * 16 + lr) * LDA + lq * 8]);
#pragma unroll
        for (int i = 0; i < 4; ++i)
#pragma unroll
            for (int j = 0; j < 4; ++j)
                acc[i][j] = __builtin_amdgcn_mfma_f32_16x16x32_f16(af[i], bf[j], acc[i][j], 0, 0, 0);
        __syncthreads();
    }

#pragma unroll
    for (int i = 0; i < 4; ++i) {
        const int gm_base = m0 + wm + i * 16 + lq * 4;
#pragma unroll
        for (int r = 0; r < 4; ++r) {
            const int gm = gm_base + r;
            if (gm < M) {
#pragma unroll
                for (int j = 0; j < 4; ++j) {
                    const int gn = n0 + wn + j * 16 + lr;
                    C[(long)gm * N + gn] = (_Float16)acc[i][j][r];
                }
            }
        }
    }
}

// --- CSR build --------------------------------------------------------------

__global__ void count_kernel(const int* __restrict__ dst, int* __restrict__ deg, int E)
{
    const int e = blockIdx.x * blockDim.x + threadIdx.x;
    if (e < E) atomicAdd(&deg[dst[e]], 1);
}

// phase 1: per-block scan of (deg[i]+1), 1024 elems/block, int4 per thread
__global__ __launch_bounds__(256) void block_scan_kernel(
    const int* __restrict__ deg, int* __restrict__ pre, int* __restrict__ blk, int n)
{
    __shared__ int s[256];
    const int t = threadIdx.x;
    const int base = blockIdx.x * 1024 + t * 4;
    int4 d = make_int4(-1, -1, -1, -1);   // -1 -> +1 = 0 contribution for OOB
    if (base + 3 < n) d = *reinterpret_cast<const int4*>(deg + base);
    else {
        if (base + 0 < n) d.x = deg[base + 0];
        if (base + 1 < n) d.y = deg[base + 1];
        if (base + 2 < n) d.z = deg[base + 2];
        if (base + 3 < n) d.w = deg[base + 3];
    }
    const int v0 = d.x + 1, v1 = d.y + 1, v2 = d.z + 1, v3 = d.w + 1;
    s[t] = v0 + v1 + v2 + v3;
    __syncthreads();
#pragma unroll
    for (int o = 1; o < 256; o <<= 1) {
        int val = 0;
        if (t >= o) val = s[t - o];
        __syncthreads();
        s[t] += val;
        __syncthreads();
    }
    int run = (t == 0) ? 0 : s[t - 1];
    int4 o4;
    o4.x = run; run += v0;
    o4.y = run; run += v1;
    o4.z = run; run += v2;
    o4.w = run; run += v3;
    if (base + 3 < n) *reinterpret_cast<int4*>(pre + base) = o4;
    else {
        if (base + 0 < n) pre[base + 0] = o4.x;
        if (base + 1 < n) pre[base + 1] = o4.y;
        if (base + 2 < n) pre[base + 2] = o4.z;
        if (base + 3 < n) pre[base + 3] = o4.w;
    }
    if (t == 255) blk[blockIdx.x] = s[255];
}

// phase 2: one wave scans the (<=64) block totals; writes off[n] = grand total
__global__ void total_scan_kernel(const int* __restrict__ blk, int* __restrict__ blk_off,
                                  int* __restrict__ off_end, int nb)
{
    const int l = threadIdx.x;
    const int self = (l < nb) ? blk[l] : 0;
    int v = self;
#pragma unroll
    for (int o = 1; o < 64; o <<= 1) {
        int u = __shfl_up(v, o, 64);
        if (l >= o) v += u;
    }
    if (l < nb) blk_off[l] = v - self;
    if (l == nb - 1) *off_end = v;
}

// phase 3: add block offsets, emit csr_off + cursor
__global__ __launch_bounds__(256) void finalize_scan_kernel(
    const int* __restrict__ pre, const int* __restrict__ blk_off,
    int* __restrict__ off, int* __restrict__ cursor, int n)
{
    const int t = threadIdx.x;
    const int base = blockIdx.x * 1024 + t * 4;
    const int add = blk_off[blockIdx.x];
    if (base + 3 < n) {
        int4 p = *reinterpret_cast<const int4*>(pre + base);
        p.x += add; p.y += add; p.z += add; p.w += add;
        *reinterpret_cast<int4*>(off + base) = p;
        *reinterpret_cast<int4*>(cursor + base) = p;
    } else {
#pragma unroll
        for (int k = 0; k < 4; ++k)
            if (base + k < n) {
                const int v = pre[base + k] + add;
                off[base + k] = v;
                cursor[base + k] = v;
            }
    }
}

__global__ void scatter_kernel(const int* __restrict__ src, const int* __restrict__ dst,
                               int* __restrict__ cursor, int* __restrict__ csr_src,
                               int E, int N)
{
    const int e = blockIdx.x * blockDim.x + threadIdx.x;
    if (e < E) {
        const int d = dst[e];
        const int p = atomicAdd(&cursor[d], 1);
        csr_src[p] = src[e];
    } else if (e < E + N) {
        const int nn = e - E;
        const int p = atomicAdd(&cursor[nn], 1);
        csr_src[p] = nn;
    }
}

// --- attention logits: a[n,h] = sum_c h[n,h,c]*att[h,c], C=128, fp16 h ------

template <int H>
__global__ __launch_bounds__(256) void att_kernel(
    const _Float16* __restrict__ h,   // [N, H*128]
    const float* __restrict__ att_s,  // [H*128]
    const float* __restrict__ att_d,  // [H*128]
    float* __restrict__ a_s,          // [N*H]
    float* __restrict__ a_d,          // [N*H]
    int N)
{
    const int g = (blockIdx.x * 256 + threadIdx.x) >> 6;  // wave id = n*H + hh
    const int l = threadIdx.x & 63;
    if (g >= N * H) return;
    const int n  = g / H;
    const int hh = g % H;
    const _Float16* row = h + (long)n * (H * 128) + hh * 128;
    const float* asv = att_s + hh * 128;
    const float* adv = att_d + hh * 128;
    const float v0 = (float)row[l], v1 = (float)row[l + 64];
    float ss = v0 * asv[l] + v1 * asv[l + 64];
    float dd = v0 * adv[l] + v1 * adv[l + 64];
#pragma unroll
    for (int o = 32; o > 0; o >>= 1) {
        ss += __shfl_xor(ss, o, 64);
        dd += __shfl_xor(dd, o, 64);
    }
    if (l == 0) { a_s[g] = ss; a_d[g] = dd; }
}

// --- pull-based aggregation (fp16 messages, fp32 accumulate) ---------------
// out[d, c] = (sum_e w_eh * h[s_e, c]) / (sum_e w_eh) [+bias][relu]
// w_eh = exp(leaky_relu(a_s[s,h] + a_d[d,h])); VPT cols per thread, 64 thr.

#define AGG_TILE 64

template <int H, int C, int VPT, bool RELU, typename TOUT>
__global__ __launch_bounds__(H * C / VPT) void aggregate_kernel(
    const int* __restrict__ csr_off,
    const int* __restrict__ csr_src,
    const _Float16* __restrict__ h,  // [N, H*C] fp16
    const float* __restrict__ a_s,   // [N, H]
    const float* __restrict__ a_d,   // [N, H]
    const float* __restrict__ bias,  // [H*C]
    TOUT* __restrict__ out)          // [N, H*C]
{
    const int d   = blockIdx.x;
    const int t   = threadIdx.x;
    const int col = t * VPT;
    const int hh  = col / C;

    __shared__ int   s_src[AGG_TILE];
    __shared__ float s_w[AGG_TILE][H];

    const int beg = csr_off[d];
    const int end = csr_off[d + 1];

    float acc[VPT] = {};
    float wsum = 0.f;

    for (int base = beg; base < end; base += AGG_TILE) {
        const int len = min(AGG_TILE, end - base);
        if (t < len) {
            const int s = csr_src[base + t];
            s_src[t] = s;
#pragma unroll
            for (int h2 = 0; h2 < H; ++h2) {
                float logit = a_s[s * H + h2] + a_d[d * H + h2];
                logit = logit > 0.f ? logit : 0.2f * logit;
                s_w[t][h2] = __expf(logit);
            }
        }
        __syncthreads();
#pragma unroll 4
        for (int j = 0; j < len; ++j) {
            const float w = s_w[j][hh];
            const int   s = s_src[j];
            if constexpr (VPT == 4) {
                half4v hv = *reinterpret_cast<const half4v*>(h + (long)s * (H * C) + col);
                acc[0] += w * (float)hv.x;
                acc[1] += w * (float)hv.y;
                acc[2] += w * (float)hv.z;
                acc[3] += w * (float)hv.w;
            } else {
                half2v hv = *reinterpret_cast<const half2v*>(h + (long)s * (H * C) + col);
                acc[0] += w * (float)hv.x;
                acc[1] += w * (float)hv.y;
            }
            wsum += w;
        }
        __syncthreads();
    }

    const float inv = 1.f / wsum;
    float r[VPT];
#pragma unroll
    for (int k = 0; k < VPT; ++k) {
        r[k] = acc[k] * inv + bias[col + k];
        if (RELU) r[k] = r[k] > 0.f ? r[k] : 0.f;
    }
    if constexpr (__is_same(TOUT, _Float16)) {
#pragma unroll
        for (int k = 0; k < VPT; ++k)
            out[(long)d * (H * C) + col + k] = (_Float16)r[k];
    } else {
#pragma unroll
        for (int k = 0; k < VPT; ++k)
            out[(long)d * (H * C) + col + k] = r[k];
    }
}

// ---------------------------------------------------------------------------

extern "C" void kernel_launch(void* const* d_in, const int* in_sizes, int n_in,
                              void* d_out, int out_size, void* d_ws, size_t ws_size,
                              hipStream_t stream)
{
    const float* x    = (const float*)d_in[0];
    const int*   eidx = (const int*)d_in[1];
    const float* W1   = (const float*)d_in[2];
    const float* as1  = (const float*)d_in[3];
    const float* ad1  = (const float*)d_in[4];
    const float* b1   = (const float*)d_in[5];
    const float* W2   = (const float*)d_in[6];
    const float* as2  = (const float*)d_in[7];
    const float* ad2  = (const float*)d_in[8];
    const float* b2   = (const float*)d_in[9];
    float* out = (float*)d_out;

    const int IN_FEATS = 256;
    const int N = in_sizes[0] / IN_FEATS;    // 50000
    const int E = in_sizes[1] / 2;           // 800000

    const int* esrc = eidx;
    const int* edst = eidx + E;

    size_t off = 0;
    auto alloc = [&](size_t bytes) -> void* {
        void* p = (char*)d_ws + off;
        off += (bytes + 255) & ~(size_t)255;
        return p;
    };
    _Float16* h1h   = (_Float16*)alloc((size_t)N * 256 * 2);
    _Float16* o1h   = (_Float16*)alloc((size_t)N * 256 * 2);
    _Float16* h2h   = (_Float16*)alloc((size_t)N * 128 * 2);
    float* a1s      = (float*)alloc((size_t)N * 2 * 4);
    float* a1d      = (float*)alloc((size_t)N * 2 * 4);
    float* a2s      = (float*)alloc((size_t)N * 4);
    float* a2d      = (float*)alloc((size_t)N * 4);
    int*   deg      = (int*)alloc((size_t)N * 4);
    int*   pre      = (int*)alloc((size_t)N * 4);
    int*   cursor   = (int*)alloc((size_t)N * 4);
    int*   csr_off  = (int*)alloc((size_t)(N + 1) * 4);
    int*   csr_src  = (int*)alloc((size_t)(E + N) * 4);
    int*   blk      = (int*)alloc(64 * 4);
    int*   blk_off  = (int*)alloc(64 * 4);

    const int nbScan = (N + 1023) / 1024;    // 49 <= 64

    // --- CSR build (same graph both layers) ---
    hipMemsetAsync(deg, 0, (size_t)N * 4, stream);
    count_kernel<<<(E + 255) / 256, 256, 0, stream>>>(edst, deg, E);
    block_scan_kernel<<<nbScan, 256, 0, stream>>>(deg, pre, blk, N);
    total_scan_kernel<<<1, 64, 0, stream>>>(blk, blk_off, csr_off + N, nbScan);
    finalize_scan_kernel<<<nbScan, 256, 0, stream>>>(pre, blk_off, csr_off, cursor, N);
    scatter_kernel<<<(E + N + 255) / 256, 256, 0, stream>>>(esrc, edst, cursor, csr_src, E, N);

    // --- layer 1 ---
    {
        dim3 grid((N + 127) / 128, 256 / 128);
        gemm_mfma_kernel<float><<<grid, 256, 0, stream>>>(x, W1, h1h, N, 256, 256);
    }
    att_kernel<2><<<(N * 2 + 3) / 4, 256, 0, stream>>>(h1h, as1, ad1, a1s, a1d, N);
    aggregate_kernel<2, 128, 4, true, _Float16><<<N, 64, 0, stream>>>(
        csr_off, csr_src, h1h, a1s, a1d, b1, o1h);

    // --- layer 2 ---
    {
        dim3 grid((N + 127) / 128, 128 / 128);
        gemm_mfma_kernel<_Float16><<<grid, 256, 0, stream>>>(o1h, W2, h2h, N, 128, 256);
    }
    att_kernel<1><<<(N + 3) / 4, 256, 0, stream>>>(h2h, as2, ad2, a2s, a2d, N);
    aggregate_kernel<1, 128, 2, false, float><<<N, 64, 0, stream>>>(
        csr_off, csr_src, h2h, a2s, a2d, b2, out);
}